// Round 3
// baseline (168.793 us; speedup 1.0000x reference)
//
#include <hip/hip_runtime.h>
#include <stdint.h>

// out = conv3x3_zeropad(s, W_eff), s = 3x3 reflect-pad box sum of x (B=16,C=64,H=W=128)
// R8 == R7 resubmit (container infra failure, kernel statically audited):
// FUSED kernel — boxsum computed per conv-block directly from x into the
// conv's swizzled LDS tile (no global s intermediate, 2 launches total).
// MFMA loop / epilogue / Wt2 A-path byte-identical to the verified R4 conv.

#define THETA 0.7f

typedef __attribute__((ext_vector_type(8))) short bf16x8;
typedef __attribute__((ext_vector_type(16))) float f32x16;

__device__ inline unsigned short f2bf(float f) {
    unsigned u = __float_as_uint(f);
    u = (u + 0x7FFFu + ((u >> 16) & 1u)) >> 16;   // RNE
    return (unsigned short)u;
}

// ---------------------------------------------------------------------------
// Kernel 1: W_eff -> Wt2 bf16, lane-contiguous MFMA-A layout (verified R5):
// Wt2[(((tap*4+ic)*2+mf)*64 + lane)*8 + j] = W_eff[o][ch][tap]
//   o = mf*32 + (lane&31), ch = ic*16 + (lane>>5)*8 + j
// ---------------------------------------------------------------------------
__global__ void weff_kernel(const float* __restrict__ W, unsigned short* __restrict__ Wt2) {
    int t = blockIdx.x * blockDim.x + threadIdx.x;   // 512 threads
    if (t >= 512) return;
    int o = t >> 3;
    int ch8 = t & 7;
    int c0 = ch8 * 8;
    int ic = ch8 >> 1;
    int mf = o >> 5;
    int lane = (o & 31) | ((ch8 & 1) << 5);

    float v[8][9];
    float tsum[8];
#pragma unroll
    for (int j = 0; j < 8; j++) {
        const float* w = W + ((size_t)o * 64 + c0 + j) * 9;
        float sum = 0.f;
#pragma unroll
        for (int k = 0; k < 9; k++) { v[j][k] = w[k]; sum += v[j][k]; }
        tsum[j] = sum;
    }
#pragma unroll
    for (int tap = 0; tap < 9; tap++) {
        unsigned short* dst = Wt2 + (((size_t)(tap * 4 + ic) * 2 + mf) * 64 + lane) * 8;
#pragma unroll
        for (int j = 0; j < 8; j++) {
            float val = v[j][tap] - ((tap == 4) ? THETA * tsum[j] : 0.f);
            dst[j] = f2bf(val);
        }
    }
}

// ---------------------------------------------------------------------------
// Staging: one s-row (66 slots x 64 ch) of the conv LDS tile, computed from x.
// Thread owns channel c. Loads 3 x-rows (vertical reflect), 17 aligned float4
// each; vertical sums into statically-indexed v[68] (v[j] <-> w = w0-2+j);
// reflect-patches edge v in registers; horizontal 3-sum; zero-pads OOB conv
// columns; writes bf16 shorts at physical unit (c>>3)^(slot&7) — the exact
// layout the verified MFMA loop reads. 64 lanes/slot span 128 consecutive
// bytes -> conflict-free ds_write_u16.
//   LEDGE  (w0==0):  loads w=0..67,  j = w+2;  patch v[0]=v[4], v[1]=v[3]
//   !LEDGE (w0==64): loads w=60..127, j = w-62; patch v[66]=v[64], v[67]=v[63]
// ---------------------------------------------------------------------------
template<bool LEDGE>
__device__ __forceinline__ void stage_row(const float* __restrict__ xb,
                                          unsigned short* sSp,
                                          int h0, int row, int c) {
    int hg = h0 - 1 + row;
    if (hg < 0 || hg > 127) return;   // OOB rows pre-zeroed (wave-uniform branch)
    const float* r0 = xb + (size_t)((hg == 0) ? 1 : hg - 1) * 128;
    const float* r1 = xb + (size_t)hg * 128;
    const float* r2 = xb + (size_t)((hg == 127) ? 126 : hg + 1) * 128;
    constexpr int xw0 = LEDGE ? 0 : 60;    // first loaded w (16B-aligned)
    constexpr int joff = LEDGE ? 2 : -2;   // j = (w - xw0) + joff

    float v[68];
#pragma unroll
    for (int k = 0; k < 17; k++) {
        float4 a = *(const float4*)(r0 + xw0 + 4 * k);
        float4 bb = *(const float4*)(r1 + xw0 + 4 * k);
        float4 cc = *(const float4*)(r2 + xw0 + 4 * k);
        float s4[4] = {a.x + bb.x + cc.x, a.y + bb.y + cc.y,
                       a.z + bb.z + cc.z, a.w + bb.w + cc.w};
#pragma unroll
        for (int e = 0; e < 4; e++) {
            int j = 4 * k + e + joff;          // compile-time (fully unrolled)
            if (j >= 0 && j < 68) v[j] = s4[e];
        }
    }
    if (LEDGE) { v[0] = v[4]; v[1] = v[3]; }       // w=-2 -> w=2, w=-1 -> w=1
    else       { v[66] = v[64]; v[67] = v[63]; }   // w=128 -> 126, w=129 -> 125

    unsigned short* base = sSp + row * 4224 + (c & 7);
    int u8 = c >> 3;
#pragma unroll
    for (int slot = 0; slot < 66; slot++) {
        float sv = v[slot] + v[slot + 1] + v[slot + 2];   // wg = w0-1+slot
        if (LEDGE && slot == 0) sv = 0.f;     // wg=-1: conv zero-pad
        if (!LEDGE && slot == 65) sv = 0.f;   // wg=128: conv zero-pad
        base[slot * 64 + ((u8 ^ (slot & 7)) << 3)] = f2bf(sv);
    }
}

// ---------------------------------------------------------------------------
// Kernel 2: fused boxsum + implicit-GEMM conv, mfma_f32_32x32x16_bf16.
// Block = (b, 4 h-rows, 64-px w-tile), 4 waves; wave = 1 row x 64 px x 64 o
// (mf=2 x nf=2, acc[2][2] of f32x16). LDS tile: 6 rows x 66 slots x 64c bf16,
// 16B units XOR-swizzled g = u ^ (slot&7) — filled by stage_row from x.
// A from global Wt2 (lane-contiguous), tap-major prefetch. Grid 1024.
// ---------------------------------------------------------------------------
__global__ __launch_bounds__(256, 2) void fused_kernel(const float* __restrict__ x,
                                                       const unsigned short* __restrict__ Wt2,
                                                       float* __restrict__ out) {
    __shared__ __align__(16) unsigned short sS[6 * 66 * 64];   // 50688 B

    int bid = blockIdx.x;
    int b = bid >> 6;
    int h0 = ((bid >> 1) & 31) * 4;
    int w0 = (bid & 1) * 64;
    int tid = threadIdx.x;
    int lane = tid & 63;
    int wv = tid >> 6;
    int n32 = lane & 31;
    int q2 = lane >> 5;

    // pre-zero OOB rows (only image-edge strips)
    int4 z = make_int4(0, 0, 0, 0);
    if (h0 == 0)
        for (int i = tid; i < 528; i += 256) *(int4*)((char*)sS + (size_t)i * 16) = z;
    if (h0 == 124)
        for (int i = tid; i < 528; i += 256) *(int4*)((char*)sS + (size_t)(5 * 528 + i) * 16) = z;

    // A-frags for tap 0: issue before staging so VMEM latency overlaps
    bf16x8 Af[8], An[8];
#pragma unroll
    for (int ic = 0; ic < 4; ic++)
#pragma unroll
        for (int mf = 0; mf < 2; mf++)
            Af[ic * 2 + mf] = *(const bf16x8*)(Wt2 + (((size_t)(0 * 4 + ic) * 2 + mf) * 64 + lane) * 8);

    // ---- staging: 6 s-rows x 64 channels; thread = (c = tid&63, wave rw) ----
    {
        int c = lane;
        int rw = wv;
        const float* xb = x + ((size_t)(b * 64 + c)) * 16384;
        if (w0 == 0) {
            stage_row<true>(xb, sS, h0, rw, c);
            if (rw < 2) stage_row<true>(xb, sS, h0, 4 + rw, c);
        } else {
            stage_row<false>(xb, sS, h0, rw, c);
            if (rw < 2) stage_row<false>(xb, sS, h0, 4 + rw, c);
        }
    }
    __syncthreads();

    // B LDS offsets (shorts) per (kx, ic); add (wv+ky)*4224 + nf*2048
    int p0[3][4];
#pragma unroll
    for (int kx = 0; kx < 3; kx++)
#pragma unroll
        for (int ic = 0; ic < 4; ic++) {
            int slot = n32 + kx;
            int g = (ic * 2 + q2) ^ (slot & 7);
            p0[kx][ic] = slot * 64 + g * 8;
        }

    f32x16 acc[2][2];
#pragma unroll
    for (int mf = 0; mf < 2; mf++)
#pragma unroll
        for (int nf = 0; nf < 2; nf++)
#pragma unroll
            for (int r = 0; r < 16; r++) acc[mf][nf][r] = 0.f;

#pragma unroll
    for (int tap = 0; tap < 9; tap++) {
        int ky = tap / 3, kx = tap % 3;
        if (tap < 8) {
#pragma unroll
            for (int ic = 0; ic < 4; ic++)
#pragma unroll
                for (int mf = 0; mf < 2; mf++)
                    An[ic * 2 + mf] = *(const bf16x8*)(Wt2 + (((size_t)((tap + 1) * 4 + ic) * 2 + mf) * 64 + lane) * 8);
        }
#pragma unroll
        for (int ic = 0; ic < 4; ic++) {
            const unsigned short* bp = sS + (size_t)(wv + ky) * 4224 + p0[kx][ic];
            bf16x8 b0 = *(const bf16x8*)(bp);
            bf16x8 b1 = *(const bf16x8*)(bp + 2048);
            acc[0][0] = __builtin_amdgcn_mfma_f32_32x32x16_bf16(Af[ic * 2 + 0], b0, acc[0][0], 0, 0, 0);
            acc[0][1] = __builtin_amdgcn_mfma_f32_32x32x16_bf16(Af[ic * 2 + 0], b1, acc[0][1], 0, 0, 0);
            acc[1][0] = __builtin_amdgcn_mfma_f32_32x32x16_bf16(Af[ic * 2 + 1], b0, acc[1][0], 0, 0, 0);
            acc[1][1] = __builtin_amdgcn_mfma_f32_32x32x16_bf16(Af[ic * 2 + 1], b1, acc[1][1], 0, 0, 0);
        }
        if (tap < 8) {
#pragma unroll
            for (int k = 0; k < 8; k++) Af[k] = An[k];
        }
    }

    // epilogue: 32x32 C/D layout col=lane&31 (pixel), row=(r&3)+8*(r>>2)+4*q2 (o)
    float* ob = out + ((size_t)b * 64) * 16384 + (size_t)(h0 + wv) * 128 + w0;
#pragma unroll
    for (int mf = 0; mf < 2; mf++)
#pragma unroll
        for (int nf = 0; nf < 2; nf++)
#pragma unroll
            for (int r = 0; r < 16; r++) {
                int o = mf * 32 + (r & 3) + 8 * (r >> 2) + 4 * q2;
                ob[(size_t)o * 16384 + nf * 32 + n32] = acc[mf][nf][r];
            }
}

// ---------------------------------------------------------------------------
extern "C" void kernel_launch(void* const* d_in, const int* in_sizes, int n_in,
                              void* d_out, int out_size, void* d_ws, size_t ws_size,
                              hipStream_t stream) {
    const float* x = (const float*)d_in[0];   // [16][64][128][128] fp32
    const float* W = (const float*)d_in[1];   // [64][64][3][3] fp32
    float* outp = (float*)d_out;

    // ws: Wt2 bf16 (73728 B); no global s intermediate anymore
    unsigned short* Wt2 = (unsigned short*)d_ws;

    weff_kernel<<<2, 256, 0, stream>>>(W, Wt2);
    fused_kernel<<<1024, 256, 0, stream>>>(x, Wt2, outp);
}